// Round 5
// baseline (1214.106 us; speedup 1.0000x reference)
//
#include <hip/hip_runtime.h>

#define B_   32
#define HW_  196
#define C_   512
#define HID_ 128
#define NBLK 18
#define RPAD 208   // padded rows per batch in anchor buffers (8 WGs x 32-row tiles max reach 204)

typedef _Float16 f16;
typedef _Float16 f16x4 __attribute__((ext_vector_type(4)));
typedef _Float16 f16x8 __attribute__((ext_vector_type(8)));
typedef float    f32x4 __attribute__((ext_vector_type(4)));

__device__ __forceinline__ float gelu_f(float x) {
    float t = tanhf(0.7978845608028654f * (x + 0.044715f * x * x * x));
    return 0.5f * x * (1.0f + t);
}

// async global->LDS, 16B per lane; LDS dest = wave-uniform base + lane*16
__device__ __forceinline__ void gl16(const void* g, void* l) {
    __builtin_amdgcn_global_load_lds((const __attribute__((address_space(1))) unsigned*)g,
                                     (__attribute__((address_space(3))) unsigned*)l, 16, 0, 0);
}

// ---------- weights: fp32 [blk][k][n] -> fp16 transposed [blk][n][k] ----------
__global__ __launch_bounds__(256) void conv_w(const float* __restrict__ W,
                                              f16* __restrict__ Wt) {
    __shared__ f16 sh[64][72];
    const int blk = blockIdx.z, k0 = blockIdx.x * 64, n0 = blockIdx.y * 64;
    const int tid = threadIdx.x;
    const float* Wb = W + (size_t)blk * C_ * C_;
    #pragma unroll
    for (int i = 0; i < 4; ++i) {
        int s = tid + i * 256, r = s >> 4, c4 = (s & 15) << 2;
        float4 v = *(const float4*)&Wb[(size_t)(k0 + r) * C_ + n0 + c4];
        sh[r][c4 + 0] = (f16)v.x; sh[r][c4 + 1] = (f16)v.y;
        sh[r][c4 + 2] = (f16)v.z; sh[r][c4 + 3] = (f16)v.w;
    }
    __syncthreads();
    #pragma unroll
    for (int i = 0; i < 2; ++i) {
        int s = tid + i * 256, r = s >> 3, c8 = (s & 7) << 3;
        f16x8 o;
        #pragma unroll
        for (int j = 0; j < 8; ++j) o[j] = sh[c8 + j][r];
        *(f16x8*)&Wt[(size_t)blk * C_ * C_ + (size_t)(n0 + r) * C_ + k0 + c8] = o;
    }
}

// ---------- zero pooled + gates + barrier counters ----------
__global__ __launch_bounds__(256) void zero_ws(float* __restrict__ p, int n) {
    int i = blockIdx.x * 256 + threadIdx.x;
    if (i < n) p[i] = 0.f;
}

// ---------- correct group-of-8 barrier ----------
// ALL threads: release fence -> syncthreads (so every thread's prior stores are
// flushed before the leader signals) -> leader release-inc + acquire-spin ->
// syncthreads -> acquire fence (so every thread's subsequent reads are fresh).
// Round-4 bug: leader signalled before teammates' atomicAdds/gate-stores issued.
__device__ __forceinline__ void group_barrier(int* __restrict__ ctr, int b, int target) {
    __threadfence();
    __syncthreads();
    if (threadIdx.x == 0) {
        __hip_atomic_fetch_add(&ctr[b], 1, __ATOMIC_RELEASE, __HIP_MEMORY_SCOPE_AGENT);
        while (__hip_atomic_load(&ctr[b], __ATOMIC_ACQUIRE, __HIP_MEMORY_SCOPE_AGENT) < target)
            __builtin_amdgcn_s_sleep(8);
    }
    __syncthreads();
    __threadfence();
}

__device__ __forceinline__ float agent_ld(const float* p) {
    return __hip_atomic_load(p, __ATOMIC_RELAXED, __HIP_MEMORY_SCOPE_AGENT);
}

// ---------- persistent full-chain kernel ----------
// 256 WGs x 512 thr (1 WG/CU, ~130.5 KB LDS). WG = (batch b = wg/8, slice j = wg%8).
// Row partition of the 196 batch rows: j<4 -> 25 rows from 25j, else 24 rows from
// 100+24(j-4). Each WG computes a padded 32-row tile (halo rows recomputed
// redundantly -> the GEMM chain has ZERO cross-WG dependencies; activation tile
// lives in LDS (Acur, 32KB, XOR-swizzled) for all 18 blocks). Only W streams from
// L2: 32KB K-tiles (K=32 x N=512), triple-buffered, counted vmcnt(4), raw s_barrier.
// Cross-WG sync only at targets 11/14/17: pool atomics -> group barrier -> WG0
// gate MLP -> group barrier -> routed-add in LDS. Anchors (blk 1/4/9) spill owned
// rows to global fp16 (visibility via the target-block barriers' fences).
__global__ __launch_bounds__(512, 1) void stage_persist(
    const float* __restrict__ x, const f16* __restrict__ Wt,
    const float* __restrict__ ball,
    const float* __restrict__ fc1w, const float* __restrict__ fc1b,
    const float* __restrict__ fc2w, const float* __restrict__ fc2b,
    const float* __restrict__ gammas,
    f16* __restrict__ anchors,    // [3][32][RPAD][512] f16
    float* __restrict__ pooled,   // [32][512]
    float* __restrict__ gates,    // [32][3][512]
    int* __restrict__ ctr,        // [32] monotonic phase counters
    float* __restrict__ out)      // [6272][512] fp32
{
    __shared__ f16 Acur[32 * 512];       // 32 KB activation tile, swizzled
    __shared__ f16 Wb3[3][16384];        // 3 x 32 KB W K-tiles [n=512][k=32], swizzled
    __shared__ float sh2[4][HID_];
    __shared__ float shh[HID_];

    const int wg = blockIdx.x, b = wg >> 3, j = wg & 7;
    const int tid = threadIdx.x, wave = tid >> 6, lane = tid & 63;
    const int m15 = lane & 15, q = lane >> 4;
    const int r0   = (j < 4) ? 25 * j : 100 + 24 * (j - 4);
    const int ownN = (j < 4) ? 25 : 24;

    // W staging constants: thread t stages 4x16B; chunk it: n=(t>>2)+128it,
    // slot = t&3, source k-quad kq = slot ^ ((n>>1)&3)  (it-independent).
    const int sn0 = tid >> 2;
    const int skq = (tid & 3) ^ ((tid >> 3) & 3);

    // ---- prologue: stage x (fp32) -> Acur (fp16, swizzled) ----
    #pragma unroll
    for (int v = 0; v < 8; ++v) {
        int idx = tid + v * 512;          // 4096 float4 chunks
        int lrow = idx >> 7;              // 128 float4 per row
        int c4 = (idx & 127) << 2;
        int rg = b * HW_ + r0 + lrow; if (rg > 6271) rg = 6271;
        float4 a = *(const float4*)&x[(size_t)rg * C_ + c4];
        f16x4 o; o[0] = (f16)a.x; o[1] = (f16)a.y; o[2] = (f16)a.z; o[3] = (f16)a.w;
        int kb = c4 >> 3;
        *(f16x4*)&Acur[lrow * 512 + ((kb ^ (lrow & 7)) << 3) + (c4 & 7)] = o;
    }
    __syncthreads();

    f32x4 acc[2][4];

    for (int blk = 0; blk < NBLK; ++blk) {
        const f16* Wblk = Wt + (size_t)blk * C_ * C_;
        #pragma unroll
        for (int rt = 0; rt < 2; ++rt)
            #pragma unroll
            for (int ct = 0; ct < 4; ++ct) acc[rt][ct] = (f32x4)0.f;

        // stage K-tiles 0,1
        #pragma unroll
        for (int it = 0; it < 4; ++it)
            gl16(Wblk + (size_t)(sn0 + it * 128) * C_ + 0 * 32 + skq * 8,
                 &Wb3[0][(tid + it * 512) * 8]);
        #pragma unroll
        for (int it = 0; it < 4; ++it)
            gl16(Wblk + (size_t)(sn0 + it * 128) * C_ + 1 * 32 + skq * 8,
                 &Wb3[1][(tid + it * 512) * 8]);

        #pragma unroll
        for (int kt = 0; kt < 16; ++kt) {
            if (kt < 15) asm volatile("s_waitcnt vmcnt(4)" ::: "memory");
            else         asm volatile("s_waitcnt vmcnt(0)" ::: "memory");
            asm volatile("s_barrier" ::: "memory");
            __builtin_amdgcn_sched_barrier(0);
            if (kt + 2 < 16) {   // stage kt+2 into buffer last read at kt-1
                const int nb = (kt + 2) % 3;
                #pragma unroll
                for (int it = 0; it < 4; ++it)
                    gl16(Wblk + (size_t)(sn0 + it * 128) * C_ + (kt + 2) * 32 + skq * 8,
                         &Wb3[nb][(tid + it * 512) * 8]);
            }
            const f16* Wbuf = Wb3[kt % 3];
            f16x8 af[2], bf[4];
            #pragma unroll
            for (int rt = 0; rt < 2; ++rt) {
                int row = rt * 16 + m15;
                int kb = kt * 4 + q;
                af[rt] = *(const f16x8*)&Acur[row * 512 + ((kb ^ (row & 7)) << 3)];
            }
            #pragma unroll
            for (int ct = 0; ct < 4; ++ct) {
                int n = wave * 64 + ct * 16 + m15;
                bf[ct] = *(const f16x8*)&Wbuf[n * 32 + ((q ^ ((n >> 1) & 3)) << 3)];
            }
            __builtin_amdgcn_s_setprio(1);
            #pragma unroll
            for (int rt = 0; rt < 2; ++rt)
                #pragma unroll
                for (int ct = 0; ct < 4; ++ct)
                    acc[rt][ct] = __builtin_amdgcn_mfma_f32_16x16x32_f16(af[rt], bf[ct], acc[rt][ct], 0, 0, 0);
            __builtin_amdgcn_s_setprio(0);
        }
        __syncthreads();   // all waves done reading Acur

        // epilogue: gelu(acc + bias) -> Acur (wave w owns cols [64w,64w+64) all rows)
        #pragma unroll
        for (int ct = 0; ct < 4; ++ct) {
            int col = wave * 64 + ct * 16 + m15;
            float bc = ball[blk * C_ + col];
            int kb = col >> 3, c7 = col & 7;
            #pragma unroll
            for (int rt = 0; rt < 2; ++rt) {
                #pragma unroll
                for (int r = 0; r < 4; ++r) {
                    int row = rt * 16 + q * 4 + r;
                    float v = gelu_f(acc[rt][ct][r] + bc);
                    Acur[row * 512 + ((kb ^ (row & 7)) << 3) + c7] = (f16)v;
                }
            }
        }
        __syncthreads();

        // anchors: coalesced spill of owned rows
        int aidx = (blk == 1) ? 0 : (blk == 4) ? 1 : (blk == 9) ? 2 : -1;
        if (aidx >= 0) {
            f16* anc = anchors + ((size_t)aidx * B_ + b) * RPAD * C_;
            for (int v = 0; ; ++v) {
                int idx = tid + v * 512;
                int lrow = idx >> 6;            // 64 f16x8 per row
                if (lrow >= ownN) break;
                int kb = idx & 63;
                f16x8 t8 = *(const f16x8*)&Acur[lrow * 512 + ((kb ^ (lrow & 7)) << 3)];
                *(f16x8*)&anc[(size_t)(r0 + lrow) * C_ + kb * 8] = t8;
            }
        }

        int t = (blk == 11) ? 0 : (blk == 14) ? 1 : (blk == 17) ? 2 : -1;
        if (t >= 0) {
            // pool: thread tid sums its column over owned rows
            {
                int kb = tid >> 3, c7 = tid & 7;
                float s = 0.f;
                for (int lrow = 0; lrow < ownN; ++lrow)
                    s += (float)Acur[lrow * 512 + ((kb ^ (lrow & 7)) << 3) + c7];
                atomicAdd(&pooled[b * C_ + tid], s * (1.f / 196.f));
            }
            // barrier: all 8 WGs of the group have pooled (and spilled anchors)
            group_barrier(ctr, b, (2 * t + 1) * 8);
            if (j == 0) {   // WG0 of group computes the gate MLP
                int g = tid >> 7, hh = tid & 127;
                const float* w1 = fc1w + (size_t)t * C_ * HID_ + hh;
                float s = 0.f;
                for (int c = g * 128; c < g * 128 + 128; ++c)
                    s += agent_ld(&pooled[b * C_ + c]) * w1[(size_t)c * HID_];
                sh2[g][hh] = s;
                __syncthreads();
                if (tid < HID_)
                    shh[tid] = gelu_f(sh2[0][tid] + sh2[1][tid] + sh2[2][tid] + sh2[3][tid]
                                      + fc1b[t * HID_ + tid]);
                __syncthreads();
                {
                    int c = tid;
                    const float* w2 = fc2w + (size_t)t * HID_ * (3 * C_) + c;
                    float l0 = fc2b[t * 3 * C_ + c];
                    float l1 = fc2b[t * 3 * C_ + C_ + c];
                    float l2 = fc2b[t * 3 * C_ + 2 * C_ + c];
                    for (int hj = 0; hj < HID_; ++hj) {
                        float h = shh[hj];
                        const float* rr = w2 + (size_t)hj * 3 * C_;
                        l0 += h * rr[0]; l1 += h * rr[C_]; l2 += h * rr[2 * C_];
                    }
                    float m  = fmaxf(l0, fmaxf(l1, l2));
                    float e0 = expf(l0 - m), e1 = expf(l1 - m), e2 = expf(l2 - m);
                    float inv = 1.f / (e0 + e1 + e2);
                    gates[((size_t)b * 3 + 0) * C_ + c] = e0 * inv;
                    gates[((size_t)b * 3 + 1) * C_ + c] = e1 * inv;
                    gates[((size_t)b * 3 + 2) * C_ + c] = e2 * inv;
                    pooled[b * C_ + c] = 0.f;     // re-zero for next target
                }
            }
            // barrier: gates visible to all 8 WGs (group_barrier fences cover
            // ALL WG0 threads' gate stores — round-4's leader-only signal raced)
            group_barrier(ctr, b, (2 * t + 2) * 8);
            // routed add: col = tid
            {
                float g0 = agent_ld(&gates[((size_t)b * 3 + 0) * C_ + tid]);
                float g1 = agent_ld(&gates[((size_t)b * 3 + 1) * C_ + tid]);
                float g2 = agent_ld(&gates[((size_t)b * 3 + 2) * C_ + tid]);
                float gamma = gammas[t];
                const f16* a0p = anchors + ((size_t)0 * B_ + b) * RPAD * C_ + tid;
                const f16* a1p = anchors + ((size_t)1 * B_ + b) * RPAD * C_ + tid;
                const f16* a2p = anchors + ((size_t)2 * B_ + b) * RPAD * C_ + tid;
                int kb = tid >> 3, c7 = tid & 7;
                if (t < 2) {
                    for (int lrow = 0; lrow < 32; ++lrow) {
                        int off = lrow * 512 + ((kb ^ (lrow & 7)) << 3) + c7;
                        size_t ro = (size_t)(r0 + lrow) * C_;
                        float v = (float)Acur[off] + gamma * (g0 * (float)a0p[ro]
                                  + g1 * (float)a1p[ro] + g2 * (float)a2p[ro]);
                        Acur[off] = (f16)v;
                    }
                } else {
                    for (int lrow = 0; lrow < ownN; ++lrow) {
                        int off = lrow * 512 + ((kb ^ (lrow & 7)) << 3) + c7;
                        size_t ro = (size_t)(r0 + lrow) * C_;
                        float v = (float)Acur[off] + gamma * (g0 * (float)a0p[ro]
                                  + g1 * (float)a1p[ro] + g2 * (float)a2p[ro]);
                        out[((size_t)b * HW_ + r0 + lrow) * C_ + tid] = v;
                    }
                }
            }
            __syncthreads();
        }
    }
}

extern "C" void kernel_launch(void* const* d_in, const int* in_sizes, int n_in,
                              void* d_out, int out_size, void* d_ws, size_t ws_size,
                              hipStream_t stream)
{
    const float* x      = (const float*)d_in[0];
    const float* blockw = (const float*)d_in[1];
    const float* blockb = (const float*)d_in[2];
    const float* fc1w   = (const float*)d_in[3];
    const float* fc1b   = (const float*)d_in[4];
    const float* fc2w   = (const float*)d_in[5];
    const float* fc2b   = (const float*)d_in[6];
    const float* gammas = (const float*)d_in[7];
    float* out = (float*)d_out;

    f16* Wt = (f16*)d_ws;                                    // 18*512*512 halfs = 9.44 MB
    f16* anchors = Wt + (size_t)NBLK * C_ * C_;              // 3*32*RPAD*512 halfs = 20.4 MB
    float* pooled = (float*)(anchors + (size_t)3 * B_ * RPAD * C_);  // 32*512
    float* gates  = pooled + (size_t)B_ * C_;                // 32*3*512
    int*   ctr    = (int*)(gates + (size_t)B_ * 3 * C_);     // 32

    const int nzero = B_ * C_ + B_ * 3 * C_ + B_;            // pooled + gates + ctr
    zero_ws<<<(nzero + 255) / 256, 256, 0, stream>>>(pooled, nzero);
    conv_w<<<dim3(8, 8, NBLK), 256, 0, stream>>>(blockw, Wt);
    stage_persist<<<256, 512, 0, stream>>>(x, Wt, blockb, fc1w, fc1b, fc2w, fc2b,
                                           gammas, anchors, pooled, gates, ctr, out);
}

// Round 6
// 385.314 us; speedup vs baseline: 3.1510x; 3.1510x over previous
//
#include <hip/hip_runtime.h>

#define B_   32
#define HW_  196
#define C_   512
#define M_   (B_*HW_)    // 6272
#define HID_ 128
#define NBLK 18

typedef _Float16 f16;
typedef _Float16 f16x2 __attribute__((ext_vector_type(2)));
typedef _Float16 f16x4 __attribute__((ext_vector_type(4)));
typedef _Float16 f16x8 __attribute__((ext_vector_type(8)));
typedef float    f32x4 __attribute__((ext_vector_type(4)));

__device__ __forceinline__ float gelu_f(float x) {
    float t = tanhf(0.7978845608028654f * (x + 0.044715f * x * x * x));
    return 0.5f * x * (1.0f + t);
}

// async global->LDS, 16B per lane; LDS dest = wave-uniform base + lane*16
__device__ __forceinline__ void gl16(const void* g, void* l) {
    __builtin_amdgcn_global_load_lds((const __attribute__((address_space(1))) unsigned*)g,
                                     (__attribute__((address_space(3))) unsigned*)l, 16, 0, 0);
}

// ---------- weights: fp32 [blk][k][n] -> fp16 transposed [blk][n][k] ----------
__global__ __launch_bounds__(256) void conv_w(const float* __restrict__ W,
                                              f16* __restrict__ Wt) {
    __shared__ f16 sh[64][72];
    const int blk = blockIdx.z, k0 = blockIdx.x * 64, n0 = blockIdx.y * 64;
    const int tid = threadIdx.x;
    const float* Wb = W + (size_t)blk * C_ * C_;
    #pragma unroll
    for (int i = 0; i < 4; ++i) {
        int s = tid + i * 256, r = s >> 4, c4 = (s & 15) << 2;
        float4 v = *(const float4*)&Wb[(size_t)(k0 + r) * C_ + n0 + c4];
        sh[r][c4 + 0] = (f16)v.x; sh[r][c4 + 1] = (f16)v.y;
        sh[r][c4 + 2] = (f16)v.z; sh[r][c4 + 3] = (f16)v.w;
    }
    __syncthreads();
    #pragma unroll
    for (int i = 0; i < 2; ++i) {
        int s = tid + i * 256, r = s >> 3, c8 = (s & 7) << 3;
        f16x8 o;
        #pragma unroll
        for (int j = 0; j < 8; ++j) o[j] = sh[c8 + j][r];
        *(f16x8*)&Wt[(size_t)blk * C_ * C_ + (size_t)(n0 + r) * C_ + k0 + c8] = o;
    }
}

// ---------- x: fp32 -> fp16 (x4 vectorized) ----------
__global__ __launch_bounds__(256) void conv_x(const float* __restrict__ in,
                                              f16* __restrict__ out) {
    int i = blockIdx.x * 256 + threadIdx.x;
    float4 a = ((const float4*)in)[i];
    f16x4 o; o[0] = (f16)a.x; o[1] = (f16)a.y; o[2] = (f16)a.z; o[3] = (f16)a.w;
    ((f16x4*)out)[i] = o;
}

// ---------- zero the pooled accumulator (32x512 fp32), once up-front ----------
__global__ __launch_bounds__(256) void zero_pooled(float* __restrict__ p) {
    p[blockIdx.x * 256 + threadIdx.x] = 0.f;
}

// ---------- MFMA GEMM: out = gelu(A[M,K]@W_blk[K,N] + b) [+ column-sum pooling] ----------
// 64x64x64 tile, 4 waves. Round-0 proven inner loop: 2-buffer 32KB LDS,
// __syncthreads drain per K-step -> 4 blocks/CU (16 waves), grid 784 <= 1024
// capacity, single occupancy round (round-3's 48KB/3-per-CU overflowed 784>768).
// NEW: chunked-XCD swizzle (T1). HW-linear id = r + 98c, XCD = id%8, so the 8
// column-blocks sharing A panel r landed on 4 DIFFERENT XCDs -> each A panel
// fetched ~4x from L3/HBM (~26MB/GEMM). Remap tile=(lin&7)*98+(lin>>3),
// r=tile>>3,c=tile&7 (bijective: 784=8*98): panel r's 8 readers now co-locate
// on one XCD; mapping is stable across the 18 GEMMs so phase i's row writes are
// L2-resident for phase i+1's reads on the same XCD.
#define BM 64
#define BN 64
#define BK 64
#define NKT (C_ / BK)   // 8
// LDS layout (halfs): tile[r][c-block] at r*64 + ((c ^ (r&7))<<3), r<64, c<8
__global__ __launch_bounds__(256, 4) void gemm_f16(
    const f16* __restrict__ A, const f16* __restrict__ Wt,
    const float* __restrict__ ball, int blk, f16* __restrict__ out,
    float* __restrict__ pooled)
{
    __shared__ f16 As[2][BM * BK];   // 2 x 8 KB
    __shared__ f16 Ws[2][BN * BK];   // 2 x 8 KB  -> 32 KB total, 4 blocks/CU
    __shared__ float spool[2][BN];   // per-batch-slot column sums (512 B)
    const int tid = threadIdx.x;
    const int wave = tid >> 6, lane = tid & 63;
    const int m15 = lane & 15, q = lane >> 4;
    const int wr = wave >> 1, wc = wave & 1;           // 2x2 wave grid, 32x32 tiles

    // chunked-XCD swizzle (bijective, 784 = 8*98)
    const int lin  = blockIdx.x + 98 * blockIdx.y;     // hw dispatch order
    const int tile = (lin & 7) * 98 + (lin >> 3);      // contiguous chunk per XCD
    const int rb   = tile >> 3, cb = tile & 7;
    const int row0 = rb * BM, col0 = cb * BN;

    const f16* Wb = Wt + (size_t)blk * C_ * C_;
    const float* bias = ball + (size_t)blk * C_;

    // staging: chunk ch = 8 rows x 64k (1KB). lane l loads row ch*8+(l>>3),
    // col-block (l&7)^(row&7), landing at LDS base+l*16 = swizzled layout.
    const int srow = lane >> 3;
    const int scol = ((lane & 7) ^ (srow & 7)) << 3;   // halfs
    const f16* aSrc[2]; const f16* wSrc[2];
    f16* aDst[2][2]; f16* wDst[2][2];
    #pragma unroll
    for (int i = 0; i < 2; ++i) {
        int ch = wave * 2 + i;                          // 8 chunks cover 64 rows
        aSrc[i] = A  + (size_t)(row0 + ch * 8 + srow) * C_ + scol;
        wSrc[i] = Wb + (size_t)(col0 + ch * 8 + srow) * C_ + scol;
        aDst[0][i] = &As[0][ch * 512]; aDst[1][i] = &As[1][ch * 512];
        wDst[0][i] = &Ws[0][ch * 512]; wDst[1][i] = &Ws[1][ch * 512];
    }

    f32x4 acc[2][2];
    #pragma unroll
    for (int i = 0; i < 2; ++i)
        #pragma unroll
        for (int j = 0; j < 2; ++j) acc[i][j] = (f32x4)0.f;

    // prefetch tile 0 -> buf 0
    #pragma unroll
    for (int i = 0; i < 2; ++i) { gl16(aSrc[i], aDst[0][i]); gl16(wSrc[i], wDst[0][i]); }

    #pragma unroll
    for (int kt = 0; kt < NKT; ++kt) {
        __syncthreads();   // drains this tile's loads + syncs buffer reuse
        int cur = kt & 1;
        if (kt + 1 < NKT) {
            int nxt = cur ^ 1, koff = (kt + 1) * BK;
            #pragma unroll
            for (int i = 0; i < 2; ++i) {
                gl16(aSrc[i] + koff, aDst[nxt][i]);
                gl16(wSrc[i] + koff, wDst[nxt][i]);
            }
        }
        const f16* Ab = &As[cur][0];
        const f16* Bb = &Ws[cur][0];
        #pragma unroll
        for (int kk = 0; kk < BK; kk += 32) {
            f16x8 af[2], bf[2];
            #pragma unroll
            for (int i = 0; i < 2; ++i) {
                int r = wr * 32 + i * 16 + m15;
                int c = (kk >> 3) + q;
                af[i] = *(const f16x8*)&Ab[r * 64 + ((c ^ (r & 7)) << 3)];
            }
            #pragma unroll
            for (int j = 0; j < 2; ++j) {
                int r = wc * 32 + j * 16 + m15;
                int c = (kk >> 3) + q;
                bf[j] = *(const f16x8*)&Bb[r * 64 + ((c ^ (r & 7)) << 3)];
            }
            __builtin_amdgcn_s_setprio(1);
            #pragma unroll
            for (int i = 0; i < 2; ++i)
                #pragma unroll
                for (int j = 0; j < 2; ++j)
                    acc[i][j] = __builtin_amdgcn_mfma_f32_16x16x32_f16(af[i], bf[j], acc[i][j], 0, 0, 0);
            __builtin_amdgcn_s_setprio(0);
        }
    }

    // epilogue: C/D layout col=lane&15, row=quad*4+reg (HW-verified, dtype-indep)
    const bool doPool = (pooled != nullptr);
    if (doPool) {
        if (tid < 2 * BN) ((float*)spool)[tid] = 0.f;
        __syncthreads();
    }
    const int bA = row0 / HW_;                 // first batch this tile touches
    float ps[2][2] = {{0.f, 0.f}, {0.f, 0.f}}; // [batch-slot][j] partial sums
    float bcol[2];
    #pragma unroll
    for (int j = 0; j < 2; ++j) bcol[j] = bias[col0 + wc * 32 + j * 16 + m15];
    #pragma unroll
    for (int i = 0; i < 2; ++i) {
        #pragma unroll
        for (int r = 0; r < 4; ++r) {
            int rloc = wr * 32 + i * 16 + q * 4 + r;
            int row = row0 + rloc;
            int slot = (row / HW_) - bA;       // 0 or 1 (tile spans <= 2 batches)
            #pragma unroll
            for (int j = 0; j < 2; ++j) {
                int col = col0 + wc * 32 + j * 16 + m15;
                float v = gelu_f(acc[i][j][r] + bcol[j]);
                out[(size_t)row * C_ + col] = (f16)v;
                if (doPool) ps[slot & 1][j] += v;
            }
        }
    }
    if (doPool) {
        #pragma unroll
        for (int s = 0; s < 2; ++s)
            #pragma unroll
            for (int j = 0; j < 2; ++j)
                atomicAdd(&spool[s][wc * 32 + j * 16 + m15], ps[s][j]);
        __syncthreads();
        if (tid < 2 * BN) {
            int slot = tid >> 6, colt = tid & 63;
            int b = bA + slot;
            int lastb = (row0 + BM - 1) / HW_;
            if (b <= lastb)                    // slot 1 only if tile spans batches
                atomicAdd(&pooled[(size_t)b * C_ + col0 + colt], spool[slot][colt]);
        }
    }
}

// ---------- gating MLP + softmax over anchors (pooled = raw column sums) ----------
// also re-zeroes its pooled row for the next target block (saves zero launches)
__global__ __launch_bounds__(256) void gate_kernel(float* __restrict__ pooled,
    const float* __restrict__ fc1w, const float* __restrict__ fc1b,
    const float* __restrict__ fc2w, const float* __restrict__ fc2b,
    int t, float* __restrict__ gates)
{
    __shared__ float sp[C_];
    __shared__ float sh2[2][HID_];
    __shared__ float sh[HID_];
    const int b = blockIdx.x, tid = threadIdx.x;

    float2 pv = *(const float2*)&pooled[b * C_ + 2 * tid];
    sp[2 * tid]     = pv.x * (1.f / 196.f);
    sp[2 * tid + 1] = pv.y * (1.f / 196.f);
    *(float2*)&pooled[b * C_ + 2 * tid] = make_float2(0.f, 0.f);  // ready for next target
    __syncthreads();

    // fc1: 2 threads per output (split C in halves), 256 iters each
    {
        int half = tid >> 7, hh = tid & 127;
        const float* w = fc1w + (size_t)t * C_ * HID_ + hh;
        float s = 0.f;
        int c0 = half * 256;
        for (int c = c0; c < c0 + 256; ++c) s += sp[c] * w[(size_t)c * HID_];
        sh2[half][hh] = s;
    }
    __syncthreads();
    if (tid < HID_) sh[tid] = gelu_f(sh2[0][tid] + sh2[1][tid] + fc1b[t * HID_ + tid]);
    __syncthreads();

    #pragma unroll
    for (int cc = 0; cc < 2; ++cc) {
        int c = tid + cc * 256;
        const float* w2 = fc2w + (size_t)t * HID_ * (3 * C_) + c;
        float l0 = fc2b[t * 3 * C_ + c];
        float l1 = fc2b[t * 3 * C_ + C_ + c];
        float l2 = fc2b[t * 3 * C_ + 2 * C_ + c];
        for (int j = 0; j < HID_; ++j) {
            float h = sh[j];
            const float* r = w2 + (size_t)j * 3 * C_;
            l0 += h * r[0];
            l1 += h * r[C_];
            l2 += h * r[2 * C_];
        }
        float m  = fmaxf(l0, fmaxf(l1, l2));
        float e0 = expf(l0 - m), e1 = expf(l1 - m), e2 = expf(l2 - m);
        float inv = 1.f / (e0 + e1 + e2);
        gates[(size_t)b * 3 * C_ + c]          = e0 * inv;
        gates[(size_t)b * 3 * C_ + C_ + c]     = e1 * inv;
        gates[(size_t)b * 3 * C_ + 2 * C_ + c] = e2 * inv;
    }
}

// ---------- nx += gamma * sum_a gates[b,a,c]*anchor_a ; t==2 also writes fp32 out ----------
// x8 vectorized: 16B f16 loads from 4 activation arrays (64 B/thread)
__global__ __launch_bounds__(256) void routed_add_kernel(f16* __restrict__ nx,
    const f16* __restrict__ a0, const f16* __restrict__ a1, const f16* __restrict__ a2,
    const float* __restrict__ gates, const float* __restrict__ gammas, int t,
    float* __restrict__ outf)
{
    int v = blockIdx.x * 256 + threadIdx.x;    // vector index (8 elems each)
    int idx = v * 8;
    int c = idx & (C_ - 1);
    int b = idx / (HW_ * C_);
    const float* g = gates + (size_t)b * 3 * C_ + c;
    float gamma = gammas[t];
    f16x8 xn = ((const f16x8*)nx)[v];
    f16x8 x0 = ((const f16x8*)a0)[v];
    f16x8 x1 = ((const f16x8*)a1)[v];
    f16x8 x2 = ((const f16x8*)a2)[v];
    float r[8];
    #pragma unroll
    for (int e = 0; e < 8; ++e)
        r[e] = (float)xn[e] + gamma * (g[e] * (float)x0[e] + g[C_ + e] * (float)x1[e]
                                       + g[2 * C_ + e] * (float)x2[e]);
    if (outf) {
        float4* o = (float4*)&outf[idx];
        o[0] = make_float4(r[0], r[1], r[2], r[3]);
        o[1] = make_float4(r[4], r[5], r[6], r[7]);
    } else {
        f16x8 o;
        #pragma unroll
        for (int e = 0; e < 8; ++e) o[e] = (f16)r[e];
        ((f16x8*)nx)[v] = o;
    }
}

extern "C" void kernel_launch(void* const* d_in, const int* in_sizes, int n_in,
                              void* d_out, int out_size, void* d_ws, size_t ws_size,
                              hipStream_t stream)
{
    const float* x      = (const float*)d_in[0];
    const float* blockw = (const float*)d_in[1];
    const float* blockb = (const float*)d_in[2];
    const float* fc1w   = (const float*)d_in[3];
    const float* fc1b   = (const float*)d_in[4];
    const float* fc2w   = (const float*)d_in[5];
    const float* fc2b   = (const float*)d_in[6];
    const float* gammas = (const float*)d_in[7];
    float* out = (float*)d_out;

    const size_t NB = (size_t)M_ * C_;            // 3,211,264 elems/activation
    f16* Wt = (f16*)d_ws;                          // 18*512*512 halfs = 9.44MB
    f16* P0 = Wt + (size_t)NBLK * C_ * C_;
    f16* P1 = P0 + NB;
    f16* A0 = P0 + 2 * NB;
    f16* A1 = P0 + 3 * NB;
    f16* A2 = P0 + 4 * NB;
    float* pooled = (float*)(P0 + 5 * NB);         // 32*512 fp32 raw column sums
    float* gates  = pooled + B_ * C_;

    zero_pooled<<<B_ * C_ / 256, 256, 0, stream>>>(pooled);  // gate_kernel re-zeroes after
    conv_w<<<dim3(8, 8, NBLK), 256, 0, stream>>>(blockw, Wt);
    conv_x<<<(int)(NB / 1024), 256, 0, stream>>>(x, P1);

    // x(fp16)=P1 feeds block 0; anchors (blocks 1,4,9 outputs) pinned A0/A1/A2
    const f16* ins[NBLK]  = {P1, P0, A0, P0, P1, A1, P0, P1, P0, P1, A2, P0, P1, P0, P1, P0, P1, P0};
    f16*       outs[NBLK] = {P0, A0, P0, P1, A1, P0, P1, P0, P1, A2, P0, P1, P0, P1, P0, P1, P0, P1};

    for (int i = 0; i < NBLK; ++i) {
        int t = (i == 11) ? 0 : (i == 14) ? 1 : (i == 17) ? 2 : -1;
        gemm_f16<<<dim3(M_ / BM, C_ / BN), 256, 0, stream>>>(
            ins[i], Wt, blockb, i, outs[i], (t >= 0) ? pooled : (float*)nullptr);
        if (t >= 0) {
            gate_kernel<<<B_, 256, 0, stream>>>(pooled, fc1w, fc1b, fc2w, fc2b, t, gates);
            routed_add_kernel<<<(int)(NB / 2048), 256, 0, stream>>>(
                outs[i], A0, A1, A2, gates, gammas, t,
                (t == 2) ? out : (float*)nullptr);
        }
    }
}